// Round 10
// baseline (105.374 us; speedup 1.0000x reference)
//
#include <hip/hip_runtime.h>
#include <hip/hip_bf16.h>
#include <math.h>

// Chamfer distance via K-packed MFMA, B=8, N=M=8192, D=3, fp32.
//   C[m][n] = q_m.r_n - 0.5*||r_n||^2 via ONE v_mfma_f32_32x32x16_bf16.
//   Record (16B) {xh|yh, zh|wh, xl|yl, zl|wl}, w = -0.5*||p||^2 (hi/lo bf16).
//   8B-load operand layout (R6-verified):
//     lanes<32  (k0-7) : A={qh,1, ql,0}  B={rh,wh, rh,wh} -> qh.rh+wh + ql.rh
//     lanes>=32 (k8-15): A={qh,1, 0,0}   B={rl,wl, 0,0}   -> qh.rl+wl
//   (dropped ql.rl ~2^-17 relative)
//   min_j d2 = ||q||^2_fp32 - 2*max_n C, clamped at 0.
// R10 = R9 with the A-fragment bug fixed: R9 wrongly used R7's A layout
// (meant for full-16B B records) with 8B B loads, computing 2(qh.rh+wh)+ql.rl.
// QPW=32 (small live set) + launch_bounds(256,5) for 5-6 waves/SIMD residency.

#define BLOCK 256
#define WAVES 4
#define QPW 32        // queries per wave (one 32-row MFMA group)
#define NCHUNK 2      // ref-dim split across blockIdx.y

typedef short short8 __attribute__((ext_vector_type(8)));
typedef float f32x16 __attribute__((ext_vector_type(16)));

union U16S { uint4 v; short8 s; };

__device__ __forceinline__ unsigned int bf16hi(float f) {
    __hip_bfloat16 h = __float2bfloat16(f);
    return (unsigned int)*reinterpret_cast<unsigned short*>(&h);
}
__device__ __forceinline__ float bf16f(unsigned int u) {
    unsigned short us = (unsigned short)u;
    __hip_bfloat16 h;
    *reinterpret_cast<unsigned short*>(&h) = us;
    return __bfloat162float(h);
}

// Per point one 16B record {xh|yh, zh|wh, xl|yl, zl|wl} + fp32 ||p||^2 in q2.
// 4 points per thread (nG, nP are multiples of 4). Also zeroes out[0].
__global__ void prep_kernel(const float* __restrict__ gts, const float* __restrict__ preds,
                            int nG, int nP, uint4* __restrict__ recG, uint4* __restrict__ recP,
                            float* __restrict__ q2, float* out) {
    const int t = blockIdx.x * blockDim.x + threadIdx.x;
    if (t == 0) out[0] = 0.0f;
    const int i0 = t * 4;
    if (i0 >= nG + nP) return;
    const float* src;
    uint4* rec;
    if (i0 < nG) { src = gts + 3 * (size_t)i0;                rec = recG + i0; }
    else         { src = preds + 3 * (size_t)(i0 - nG);       rec = recP + (i0 - nG); }
    const float4 f0 = ((const float4*)src)[0];
    const float4 f1 = ((const float4*)src)[1];
    const float4 f2 = ((const float4*)src)[2];
    const float xs[4] = {f0.x, f0.w, f1.z, f2.y};
    const float ys[4] = {f0.y, f1.x, f1.w, f2.z};
    const float zs[4] = {f0.z, f1.y, f2.x, f2.w};
    float4 q2v;
    #pragma unroll
    for (int i = 0; i < 4; ++i) {
        const float x = xs[i], y = ys[i], z = zs[i];
        const float n2 = x * x + y * y + z * z;
        ((float*)&q2v)[i] = n2;
        const float w = -0.5f * n2;
        const unsigned int xh = bf16hi(x), yh = bf16hi(y), zh = bf16hi(z), wh = bf16hi(w);
        const unsigned int xl = bf16hi(x - bf16f(xh));
        const unsigned int yl = bf16hi(y - bf16f(yh));
        const unsigned int zl = bf16hi(z - bf16f(zh));
        const unsigned int wl = bf16hi(w - bf16f(wh));
        rec[i] = make_uint4(xh | (yh << 16), zh | (wh << 16),
                            xl | (yl << 16), zl | (wl << 16));
    }
    ((float4*)q2)[t] = q2v;      // q2 indexed globally over [0, nG+nP)
}

// kpart layout: float kpart[NCHUNK][nG + nP]; slot = blockIdx.y.
__global__ void __launch_bounds__(BLOCK, 5)
nn_kernel(const uint4* __restrict__ recG, const uint4* __restrict__ recP,
          float* __restrict__ kpart, int N, int M, int B) {
    const int z = blockIdx.z;
    const bool dirX = (z < B);
    const int b = dirX ? z : z - B;
    const int NQ = dirX ? N : M;
    const int NR = dirX ? M : N;
    const uint4* Qr = (dirX ? recG : recP) + (size_t)b * NQ;
    const uint4* Rr = (dirX ? recP : recG) + (size_t)b * NR;
    const int nGP = B * N + B * M;
    float* outK = kpart + (size_t)blockIdx.y * nGP + (dirX ? 0 : B * N) + (size_t)b * NQ;

    const int tid = threadIdx.x;
    const int lane = tid & 63;
    const int wave = tid >> 6;
    const int m = lane & 31;
    const bool hiK = lane >= 32;              // this half supplies k=8..15
    const int qBase = (blockIdx.x * WAVES + wave) * QPW;

    // ---- A fragment (R6-verified layout for 8B B-loads):
    //   lanes<32 : {qh,1, ql,0}    lanes>=32: {qh,1, 0,0}
    const uint4 q0 = Qr[qBase + m];
    U16S a;
    a.v.x = q0.x;                                   // (qxh, qyh)
    a.v.y = (q0.y & 0xFFFFu) | 0x3F800000u;         // (qzh, 1.0bf16)
    a.v.z = hiK ? 0u : q0.z;                        // (qxl, qyl) | 0
    a.v.w = hiK ? 0u : (q0.w & 0xFFFFu);            // (qzl, 0)   | 0
    const short8 A = a.s;

    const f32x16 zc = (f32x16)0.0f;
    f32x16 k;
    #pragma unroll
    for (int r = 0; r < 16; ++r) k[r] = -INFINITY;

    // B stream: per ref point 2 uint2 {hi8, lo8}; lane reads its half of
    // point m of each 32-ref tile (512 B/tile/wave, coalesced).
    const int chunk = NR / NCHUNK;
    const uint2* p = (const uint2*)(Rr + (size_t)blockIdx.y * chunk) + 2 * m + (hiK ? 1 : 0);
    const int iters = chunk / 64;             // 2 tiles (64 refs) per iter-unit

    uint2 t0 = p[0], t1 = p[64];
    #pragma unroll 1
    for (int it = 0; it < iters; it += 2) {
        // prefetch next pair; final overrun lands in adjacent ws region (safe)
        uint2 n0 = p[128], n1 = p[192];
        {
            U16S b0, b1;
            b0.v.x = t0.x; b0.v.y = t0.y;
            b0.v.z = hiK ? 0u : t0.x; b0.v.w = hiK ? 0u : t0.y;
            b1.v.x = t1.x; b1.v.y = t1.y;
            b1.v.z = hiK ? 0u : t1.x; b1.v.w = hiK ? 0u : t1.y;
            const f32x16 c0 = __builtin_amdgcn_mfma_f32_32x32x16_bf16(A, b0.s, zc, 0, 0, 0);
            const f32x16 c1 = __builtin_amdgcn_mfma_f32_32x32x16_bf16(A, b1.s, zc, 0, 0, 0);
            #pragma unroll
            for (int r = 0; r < 16; ++r)
                k[r] = fmaxf(fmaxf(c0[r], c1[r]), k[r]);   // v_max3
        }
        t0 = p[256]; t1 = p[320];
        {
            U16S b0, b1;
            b0.v.x = n0.x; b0.v.y = n0.y;
            b0.v.z = hiK ? 0u : n0.x; b0.v.w = hiK ? 0u : n0.y;
            b1.v.x = n1.x; b1.v.y = n1.y;
            b1.v.z = hiK ? 0u : n1.x; b1.v.w = hiK ? 0u : n1.y;
            const f32x16 c0 = __builtin_amdgcn_mfma_f32_32x32x16_bf16(A, b0.s, zc, 0, 0, 0);
            const f32x16 c1 = __builtin_amdgcn_mfma_f32_32x32x16_bf16(A, b1.s, zc, 0, 0, 0);
            #pragma unroll
            for (int r = 0; r < 16; ++r)
                k[r] = fmaxf(fmaxf(c0[r], c1[r]), k[r]);
        }
        p += 256;
    }

    // ---- epilogue: LDS transpose (wave-private), lane<32 max-reduces a row.
    // C/D layout: col=lane&31, row=(r&3)+8*(r>>2)+4*(lane>>5).
    __shared__ float sT[WAVES][32][36];       // stride 144B: float4-aligned
    #pragma unroll
    for (int r = 0; r < 16; ++r) {
        const int row = (r & 3) + 8 * (r >> 2) + 4 * (lane >> 5);
        sT[wave][row][m] = k[r];
    }
    if (lane < 32) {
        const float4* rowp = (const float4*)&sT[wave][lane][0];
        float4 m01 = rowp[0];
        #pragma unroll
        for (int kk = 1; kk < 8; ++kk) {
            const float4 tt = rowp[kk];
            m01.x = fmaxf(m01.x, tt.x); m01.y = fmaxf(m01.y, tt.y);
            m01.z = fmaxf(m01.z, tt.z); m01.w = fmaxf(m01.w, tt.w);
        }
        const float cmax = fmaxf(fmaxf(m01.x, m01.y), fmaxf(m01.z, m01.w));
        outK[qBase + lane] = cmax;            // coalesced, no atomics
    }
}

// d2 = max(0, q2 - 2*max(kpart[0], kpart[1])); weighted means, one
// atomicAdd per block.
__global__ void __launch_bounds__(BLOCK)
reduce_kernel(const float* __restrict__ kpart, const float* __restrict__ q2,
              int nG, int nP, float invx, float invy, float* __restrict__ out) {
    const int total = nG + nP;
    float local = 0.0f;
    for (int idx = blockIdx.x * blockDim.x + threadIdx.x; idx < total;
         idx += gridDim.x * blockDim.x) {
        const float c = fmaxf(kpart[idx], kpart[total + idx]);
        const float inv = (idx < nG) ? invx : invy;
        local += fmaxf(q2[idx] - 2.0f * c, 0.0f) * inv;
    }
    __shared__ float waveSums[BLOCK / 64];
    float v = local;
    #pragma unroll
    for (int off = 32; off; off >>= 1) v += __shfl_xor(v, off);
    if ((threadIdx.x & 63) == 0) waveSums[threadIdx.x >> 6] = v;
    __syncthreads();
    if (threadIdx.x == 0) {
        float s = 0.0f;
        #pragma unroll
        for (int w = 0; w < BLOCK / 64; ++w) s += waveSums[w];
        atomicAdd(out, s);
    }
}

extern "C" void kernel_launch(void* const* d_in, const int* in_sizes, int n_in,
                              void* d_out, int out_size, void* d_ws, size_t ws_size,
                              hipStream_t stream) {
    const float* gts   = (const float*)d_in[0];   // [B, N, 3]
    const float* preds = (const float*)d_in[1];   // [B, M, 3]
    float* out = (float*)d_out;

    const int B = 8;
    const int N = in_sizes[0] / (B * 3);
    const int M = in_sizes[1] / (B * 3);
    const int nG = B * N, nP = B * M;

    uint4* recG  = (uint4*)d_ws;                  // nG uint4 (1 MB)
    uint4* recP  = recG + nG;                     // nP uint4 (1 MB)
    float* q2    = (float*)(recP + nP);           // nG+nP floats (0.5 MB)
    float* kpart = q2 + (nG + nP);                // NCHUNK*(nG+nP) floats (1 MB)

    prep_kernel<<<((nG + nP) / 4 + BLOCK - 1) / BLOCK, BLOCK, 0, stream>>>(
        gts, preds, nG, nP, recG, recP, q2, out);

    dim3 grid(N / (WAVES * QPW), NCHUNK, 2 * B);  // 64 x 2 x 16 = 2048 blocks
    nn_kernel<<<grid, BLOCK, 0, stream>>>(recG, recP, kpart, N, M, B);

    reduce_kernel<<<256, BLOCK, 0, stream>>>(
        kpart, q2, nG, nP, 1.0f / (float)nG, 1.0f / (float)nP, out);
}